// Round 6
// baseline (107.791 us; speedup 1.0000x reference)
//
#include <hip/hip_runtime.h>

// Signed distance transform, N=192^3, exact separable EDT, packed-u16 pipeline.
//   scan (axis 2, contiguous): wave-per-line ballot bitmask EDT -> u16 d^2
//       (dist to nearest seed = min(ctz(U>>p), ctz(rev(U)>>(191-p))); no LDS)
//   axis 1 (stride NN) / axis 0 (stride NN2): outward-expansion min-plus on
//       PAIRS of k-adjacent lines packed lo/hi u16 in u32 (v_pk_add/min_u16),
//       ballot early-exit at all d <= (r+2)^2; r>38 -> float full fallback.
//   dispatch: scan -> ax1(A) -> {ax1(B) | ax0(A)} merged -> ax0(B)+tanh.
// A = d^2 to nearest zero of x (ws), B = d^2 to nearest nonzero (ws+14MB).

typedef unsigned short u16;
typedef unsigned int   u32;
typedef unsigned long long u64;
typedef u16 u16x2 __attribute__((ext_vector_type(2)));

#define NN    192
#define NN2   (192 * 192)
#define NN3   (192 * 192 * 192)

#define LINES 64
#define PAIRS 32
#define PADL  40
#define SROW  278            // words: 40 pad + 192 data + 46 pad
#define SENT16 50000
#define SENTPK 0xC350C350u

__device__ __forceinline__ u16x2 pkmin(u16x2 a, u16x2 b) { return __builtin_elementwise_min(a, b); }
__device__ __forceinline__ u16x2 pkmax(u16x2 a, u16x2 b) { return __builtin_elementwise_max(a, b); }

// ---------------------------------------------------------------------------
// Wave-parallel 1D binary EDT along contiguous axis via 192-bit masks.
// ---------------------------------------------------------------------------
__device__ __forceinline__ u64 shr_pair(u64 lo, u64 hi, int s) {
    return (lo >> s) | (s ? (hi << ((64 - s) & 63)) : 0ULL);
}
__device__ __forceinline__ int dist3(u64 a0, u64 a1, u64 a2, int s) {
    u64 w0 = shr_pair(a0, a1, s);
    u64 w1 = shr_pair(a1, a2, s);
    u64 w2 = a2 >> s;
    int t0 = w0 ? __builtin_ctzll(w0) : 255;
    int t1 = w1 ? 64 + __builtin_ctzll(w1) : 255;
    int t2 = w2 ? 128 + __builtin_ctzll(w2) : 255;
    int r = t0 < t1 ? t0 : t1;
    return r < t2 ? r : t2;
}
__device__ __forceinline__ void line_edt(u64 m0, u64 m1, u64 m2, int lane,
                                         u16& o0, u16& o1, u16& o2) {
    u64 r0 = __builtin_bitreverse64(m2);
    u64 r1 = __builtin_bitreverse64(m1);
    u64 r2 = __builtin_bitreverse64(m0);
    const int s = lane, t = 63 - lane;
    int f0 = dist3(m0, m1, m2, s);      // p = lane
    int f1 = dist3(m1, m2, 0ULL, s);    // p = lane+64
    int f2 = dist3(m2, 0ULL, 0ULL, s);  // p = lane+128
    int b0 = dist3(r2, 0ULL, 0ULL, t);  // p' = 191-p = 128+t
    int b1 = dist3(r1, r2, 0ULL, t);    // p' = 64+t
    int b2 = dist3(r0, r1, r2, t);      // p' = t
    int d0 = f0 < b0 ? f0 : b0;
    int d1 = f1 < b1 ? f1 : b1;
    int d2 = f2 < b2 ? f2 : b2;
    o0 = (d0 > 191) ? (u16)65535 : (u16)(d0 * d0);
    o1 = (d1 > 191) ? (u16)65535 : (u16)(d1 * d1);
    o2 = (d2 > 191) ? (u16)65535 : (u16)(d2 * d2);
}

__global__ __launch_bounds__(256) void sdt_scan_k(const float* __restrict__ x,
                                                  u16* __restrict__ A,
                                                  u16* __restrict__ B) {
    const int lane = threadIdx.x & 63;
    const int wid = blockIdx.x * 4 + (threadIdx.x >> 6); // wave = one line
    const size_t base = (size_t)wid * NN;
    float v0 = x[base + lane];
    float v1 = x[base + lane + 64];
    float v2 = x[base + lane + 128];
    u64 m0 = __ballot(v0 != 0.0f);
    u64 m1 = __ballot(v1 != 0.0f);
    u64 m2 = __ballot(v2 != 0.0f);
    u16 a0, a1, a2, b0, b1, b2;
    line_edt(~m0, ~m1, ~m2, lane, a0, a1, a2);  // A: seeds = zeros of x
    line_edt(m0, m1, m2, lane, b0, b1, b2);     // B: seeds = nonzeros
    A[base + lane] = a0; A[base + lane + 64] = a1; A[base + lane + 128] = a2;
    B[base + lane] = b0; B[base + lane + 64] = b1; B[base + lane + 128] = b2;
}

// ---------------------------------------------------------------------------
// One 64-line tile expansion pass, packed pairs, in-place u16.
// ES = element stride (NN for axis 1, NN2 for axis 0); lines along k (contig).
// FUSE: tanh epilogue (final axis-0 pass on B; reads final A, writes float).
// ---------------------------------------------------------------------------
template<long ES, bool FUSE>
__device__ __forceinline__ void pass_tile(u16* __restrict__ f, int g,
                                          const u16* __restrict__ other,
                                          float* __restrict__ outp,
                                          u32* ldsw) {
    const int tid = threadIdx.x;
    const int gp = g / 3, gk = g - 3 * gp;
    const size_t base = (ES == NN) ? ((size_t)gp * NN2 + (size_t)gk * 64)
                                   : ((size_t)gp * NN + (size_t)gk * 64);
    const u16x2 sentv = {(u16)SENT16, (u16)SENT16};

    // sentinel pads: words [0,40) and [232,278) per pair row
    for (int idx = tid; idx < PAIRS * 86; idx += 256) {
        int p = idx / 86, c = idx - p * 86;
        int word = (c < PADL) ? c : (c + NN);
        ldsw[p * SROW + word] = SENTPK;
    }
    // stage in (pack k-adjacent line pairs; remap 65535 -> 50000 via pk_min)
    for (int idx = tid; idx < NN * (PAIRS / 2); idx += 256) {
        int j = idx >> 4, pp = idx & 15;
        uint2 v = *(const uint2*)(f + base + (size_t)j * ES + 4 * pp);
        u16x2 a = pkmin(__builtin_bit_cast(u16x2, v.x), sentv);
        u16x2 b = pkmin(__builtin_bit_cast(u16x2, v.y), sentv);
        ldsw[(2 * pp) * SROW + PADL + j]     = __builtin_bit_cast(u32, a);
        ldsw[(2 * pp + 1) * SROW + PADL + j] = __builtin_bit_cast(u32, b);
    }
    __syncthreads();

    const int lane = tid & 63;
    const int w = tid >> 6;
    const int i0 = lane, i1 = lane + 64, i2 = lane + 128;

    for (int pp = 0; pp < 8; ++pp) {
        u16x2* rp = (u16x2*)(ldsw + (w * 8 + pp) * SROW + PADL);
        u16x2 d0 = rp[i0], d1 = rp[i1], d2 = rp[i2];

        int r = 1;
        bool conv = false;
        while (true) {
            u16 rr1 = (u16)(r * r), rr2 = (u16)((r + 1) * (r + 1));
            u16x2 q1 = {rr1, rr1}, q2 = {rr2, rr2};
            {
                u16x2 l1 = rp[i0 - r - 1], l0 = rp[i0 - r];
                u16x2 r0 = rp[i0 + r],     r1v = rp[i0 + r + 1];
                d0 = pkmin(d0, pkmin(l0 + q1, l1 + q2));
                d0 = pkmin(d0, pkmin(r0 + q1, r1v + q2));
            }
            {
                u16x2 l1 = rp[i1 - r - 1], l0 = rp[i1 - r];
                u16x2 r0 = rp[i1 + r],     r1v = rp[i1 + r + 1];
                d1 = pkmin(d1, pkmin(l0 + q1, l1 + q2));
                d1 = pkmin(d1, pkmin(r0 + q1, r1v + q2));
            }
            {
                u16x2 l1 = rp[i2 - r - 1], l0 = rp[i2 - r];
                u16x2 r0 = rp[i2 + r],     r1v = rp[i2 + r + 1];
                d2 = pkmin(d2, pkmin(l0 + q1, l1 + q2));
                d2 = pkmin(d2, pkmin(r0 + q1, r1v + q2));
            }
            u16x2 m = pkmax(pkmax(d0, d1), d2);
            unsigned mm = (m.x > m.y) ? m.x : m.y;
            unsigned thr = (unsigned)((r + 2) * (r + 2));
            if (__all(mm <= thr)) { conv = true; break; }
            r += 2;
            if (r > 37) break;   // processed radii <= 38
        }
        if (!conv) {
            u16x2 m = pkmax(pkmax(d0, d1), d2);
            unsigned mm = (m.x > m.y) ? m.x : m.y;
            if (__any(mm > 1521u)) {
                // exact full-line fallback (float domain), both packed halves
                const float fi0 = (float)i0, fi1 = (float)i1, fi2 = (float)i2;
                float e0l = 3e38f, e0h = 3e38f, e1l = 3e38f, e1h = 3e38f;
                float e2l = 3e38f, e2h = 3e38f;
                for (int j = 0; j < NN; ++j) {
                    u16x2 gv = rp[j];
                    float gl = (float)gv.x, gh = (float)gv.y;
                    float jf = (float)j;
                    float t0 = jf - fi0, t1 = jf - fi1, t2 = jf - fi2;
                    float s0 = t0 * t0, s1 = t1 * t1, s2 = t2 * t2;
                    e0l = fminf(e0l, s0 + gl); e0h = fminf(e0h, s0 + gh);
                    e1l = fminf(e1l, s1 + gl); e1h = fminf(e1h, s1 + gh);
                    e2l = fminf(e2l, s2 + gl); e2h = fminf(e2h, s2 + gh);
                }
                d0.x = (u16)fminf((float)d0.x, e0l); d0.y = (u16)fminf((float)d0.y, e0h);
                d1.x = (u16)fminf((float)d1.x, e1l); d1.y = (u16)fminf((float)d1.y, e1h);
                d2.x = (u16)fminf((float)d2.x, e2l); d2.y = (u16)fminf((float)d2.y, e2h);
            }
        }
        // wave owns this pair row; its reads completed (in-order DS)
        rp[i0] = d0; rp[i1] = d1; rp[i2] = d2;
    }
    __syncthreads();

    // stage out
    if (!FUSE) {
        for (int idx = tid; idx < NN * (PAIRS / 2); idx += 256) {
            int j = idx >> 4, pp = idx & 15;
            uint2 v;
            v.x = ldsw[(2 * pp) * SROW + PADL + j];
            v.y = ldsw[(2 * pp + 1) * SROW + PADL + j];
            *(uint2*)(f + base + (size_t)j * ES + 4 * pp) = v;
        }
    } else {
        for (int idx = tid; idx < NN * (PAIRS / 2); idx += 256) {
            int j = idx >> 4, pp = idx & 15;
            u16x2 wlo = __builtin_bit_cast(u16x2, ldsw[(2 * pp) * SROW + PADL + j]);
            u16x2 whi = __builtin_bit_cast(u16x2, ldsw[(2 * pp + 1) * SROW + PADL + j]);
            size_t ga = base + (size_t)j * ES + 4 * pp;
            ushort4 av = *(const ushort4*)(other + ga);
            float bq[4] = {(float)wlo.x, (float)wlo.y, (float)whi.x, (float)whi.y};
            float aq[4] = {(float)av.x, (float)av.y, (float)av.z, (float)av.w};
            float rq[4];
#pragma unroll
            for (int k = 0; k < 4; ++k) {
                float xx = (sqrtf(aq[k]) - sqrtf(bq[k])) * 0.1f;
                float e = __expf(2.f * xx);
                rq[k] = 1.f - 2.f * __builtin_amdgcn_rcpf(e + 1.f);
            }
            *(float4*)(outp + ga) = *(float4*)(rq);
        }
    }
}

__global__ __launch_bounds__(256) void sdt_ax1A(u16* __restrict__ A) {
    __shared__ __align__(16) u32 ldsw[PAIRS * SROW]; // 35,584 B -> 4 blocks/CU
    pass_tile<NN, false>(A, blockIdx.x, nullptr, nullptr, ldsw);
}

// merged: g<576 -> axis1 on B (heavy); g>=576 -> axis0 on A (light, final A)
__global__ __launch_bounds__(256) void sdt_mid(u16* __restrict__ A, u16* __restrict__ B) {
    __shared__ __align__(16) u32 ldsw[PAIRS * SROW];
    int g = blockIdx.x;
    if (g < 576) pass_tile<NN, false>(B, g, nullptr, nullptr, ldsw);
    else         pass_tile<NN2, false>(A, g - 576, nullptr, nullptr, ldsw);
}

__global__ __launch_bounds__(256) void sdt_ax0Bf(u16* __restrict__ B,
                                                 const u16* __restrict__ A,
                                                 float* __restrict__ outp) {
    __shared__ __align__(16) u32 ldsw[PAIRS * SROW];
    pass_tile<NN2, true>(B, blockIdx.x, A, outp, ldsw);
}

extern "C" void kernel_launch(void* const* d_in, const int* in_sizes, int n_in,
                              void* d_out, int out_size, void* d_ws, size_t ws_size,
                              hipStream_t stream) {
    const float* x = (const float*)d_in[0];
    u16* A = (u16*)d_ws;
    u16* B = (u16*)((char*)d_ws + (size_t)NN3 * 2);
    float* out = (float*)d_out;

    sdt_scan_k<<<NN2 / 4, 256, 0, stream>>>(x, A, B);
    sdt_ax1A<<<576, 256, 0, stream>>>(A);
    sdt_mid<<<1152, 256, 0, stream>>>(A, B);
    sdt_ax0Bf<<<576, 256, 0, stream>>>(B, A, out);
}

// Round 7
// 97.492 us; speedup vs baseline: 1.1056x; 1.1056x over previous
//
#include <hip/hip_runtime.h>

// Signed distance transform, N=192^3, exact separable EDT, packed-u16 pipeline.
//   scan (axis 2, contiguous): wave-per-line ballot bitmask EDT -> u16 d^2
//   axis 1 (stride NN) / axis 0 (stride NN2): outward-expansion min-plus on
//       PAIRS of k-adjacent lines packed lo/hi u16 in u32 (v_pk_add/min_u16),
//       4 radii per iteration, ballot early-exit at all d <= (r+4)^2;
//       r>40 needed -> float full-line fallback (exactness guaranteed).
//   16 pair-rows/block (17.8 KB LDS) -> 8 blocks/CU = 32 waves/CU.
//   dispatch: scan -> ax1(A) -> {ax1(B) | ax0(A)} merged -> ax0(B)+tanh.
// A = d^2 to nearest zero of x (ws), B = d^2 to nearest nonzero (ws+14MB).

typedef unsigned short u16;
typedef unsigned int   u32;
typedef unsigned long long u64;
typedef u16 u16x2 __attribute__((ext_vector_type(2)));

#define NN    192
#define NN2   (192 * 192)
#define NN3   (192 * 192 * 192)

#define PAIRS 16
#define PADL  40
#define SROW  278            // words: 40 pad + 192 data + 46 pad
#define SENT16 50000
#define SENTPK 0xC350C350u

__device__ __forceinline__ u16x2 pkmin(u16x2 a, u16x2 b) { return __builtin_elementwise_min(a, b); }
__device__ __forceinline__ u16x2 pkmax(u16x2 a, u16x2 b) { return __builtin_elementwise_max(a, b); }

// ---------------------------------------------------------------------------
// Wave-parallel 1D binary EDT along contiguous axis via 192-bit masks.
// ---------------------------------------------------------------------------
__device__ __forceinline__ u64 shr_pair(u64 lo, u64 hi, int s) {
    return (lo >> s) | (s ? (hi << ((64 - s) & 63)) : 0ULL);
}
__device__ __forceinline__ int dist3(u64 a0, u64 a1, u64 a2, int s) {
    u64 w0 = shr_pair(a0, a1, s);
    u64 w1 = shr_pair(a1, a2, s);
    u64 w2 = a2 >> s;
    int t0 = w0 ? __builtin_ctzll(w0) : 255;
    int t1 = w1 ? 64 + __builtin_ctzll(w1) : 255;
    int t2 = w2 ? 128 + __builtin_ctzll(w2) : 255;
    int r = t0 < t1 ? t0 : t1;
    return r < t2 ? r : t2;
}
__device__ __forceinline__ void line_edt(u64 m0, u64 m1, u64 m2, int lane,
                                         u16& o0, u16& o1, u16& o2) {
    u64 r0 = __builtin_bitreverse64(m2);
    u64 r1 = __builtin_bitreverse64(m1);
    u64 r2 = __builtin_bitreverse64(m0);
    const int s = lane, t = 63 - lane;
    int f0 = dist3(m0, m1, m2, s);
    int f1 = dist3(m1, m2, 0ULL, s);
    int f2 = dist3(m2, 0ULL, 0ULL, s);
    int b0 = dist3(r2, 0ULL, 0ULL, t);
    int b1 = dist3(r1, r2, 0ULL, t);
    int b2 = dist3(r0, r1, r2, t);
    int d0 = f0 < b0 ? f0 : b0;
    int d1 = f1 < b1 ? f1 : b1;
    int d2 = f2 < b2 ? f2 : b2;
    o0 = (d0 > 191) ? (u16)65535 : (u16)(d0 * d0);
    o1 = (d1 > 191) ? (u16)65535 : (u16)(d1 * d1);
    o2 = (d2 > 191) ? (u16)65535 : (u16)(d2 * d2);
}

__global__ __launch_bounds__(256) void sdt_scan_k(const float* __restrict__ x,
                                                  u16* __restrict__ A,
                                                  u16* __restrict__ B) {
    const int lane = threadIdx.x & 63;
    const int wid = blockIdx.x * 4 + (threadIdx.x >> 6);
    const size_t base = (size_t)wid * NN;
    float v0 = x[base + lane];
    float v1 = x[base + lane + 64];
    float v2 = x[base + lane + 128];
    u64 m0 = __ballot(v0 != 0.0f);
    u64 m1 = __ballot(v1 != 0.0f);
    u64 m2 = __ballot(v2 != 0.0f);
    u16 a0, a1, a2, b0, b1, b2;
    line_edt(~m0, ~m1, ~m2, lane, a0, a1, a2);
    line_edt(m0, m1, m2, lane, b0, b1, b2);
    A[base + lane] = a0; A[base + lane + 64] = a1; A[base + lane + 128] = a2;
    B[base + lane] = b0; B[base + lane + 64] = b1; B[base + lane + 128] = b2;
}

// ---------------------------------------------------------------------------
// One 32-line tile expansion pass (16 packed pair-rows), in-place u16.
// ES = element stride (NN -> axis 1, NN2 -> axis 0); lines contiguous along k.
// FUSE: tanh epilogue (final axis-0 pass on B; reads final A, writes float).
// ---------------------------------------------------------------------------
template<long ES, bool FUSE>
__device__ __forceinline__ void pass_tile(u16* __restrict__ f, int g,
                                          const u16* __restrict__ other,
                                          float* __restrict__ outp,
                                          u32* ldsw) {
    const int tid = threadIdx.x;
    const int gp = g / 6, gk = g - 6 * gp;
    const size_t base = (ES == NN ? (size_t)gp * NN2 : (size_t)gp * NN) + (size_t)gk * 32;
    const u16x2 sentv = {(u16)SENT16, (u16)SENT16};

    // sentinel pads: words [0,40) and [232,278) per pair row
    for (int idx = tid; idx < PAIRS * 86; idx += 256) {
        int p = idx / 86, c = idx - p * 86;
        int word = (c < PADL) ? c : (c + NN);
        ldsw[p * SROW + word] = SENTPK;
    }
    // stage in (pack k-adjacent line pairs; remap 65535 -> 50000 via pk_min)
    for (int idx = tid; idx < NN * (PAIRS / 2); idx += 256) {
        int j = idx >> 3, pp = idx & 7;
        uint2 v = *(const uint2*)(f + base + (size_t)j * ES + 4 * pp);
        u16x2 a = pkmin(__builtin_bit_cast(u16x2, v.x), sentv);
        u16x2 b = pkmin(__builtin_bit_cast(u16x2, v.y), sentv);
        ldsw[(2 * pp) * SROW + PADL + j]     = __builtin_bit_cast(u32, a);
        ldsw[(2 * pp + 1) * SROW + PADL + j] = __builtin_bit_cast(u32, b);
    }
    __syncthreads();

    const int lane = tid & 63;
    const int w = tid >> 6;
    const int i0 = lane, i1 = lane + 64, i2 = lane + 128;

    for (int pp = 0; pp < 4; ++pp) {
        u16x2* rp = (u16x2*)(ldsw + (w * 4 + pp) * SROW + PADL);
        u16x2 d0 = rp[i0], d1 = rp[i1], d2 = rp[i2];

        int r = 1;
        bool conv = false;
        while (true) {
            u16 c1 = (u16)(r * r),           c2 = (u16)((r + 1) * (r + 1));
            u16 c3 = (u16)((r + 2) * (r + 2)), c4 = (u16)((r + 3) * (r + 3));
            u16x2 q1 = {c1, c1}, q2 = {c2, c2}, q3 = {c3, c3}, q4 = {c4, c4};
            {
                u16x2 La = rp[i0 - r], Lb = rp[i0 - r - 1], Lc = rp[i0 - r - 2], Ld = rp[i0 - r - 3];
                u16x2 Ra = rp[i0 + r], Rb = rp[i0 + r + 1], Rc = rp[i0 + r + 2], Rd = rp[i0 + r + 3];
                d0 = pkmin(d0, pkmin(pkmin(La + q1, Lb + q2), pkmin(Lc + q3, Ld + q4)));
                d0 = pkmin(d0, pkmin(pkmin(Ra + q1, Rb + q2), pkmin(Rc + q3, Rd + q4)));
            }
            {
                u16x2 La = rp[i1 - r], Lb = rp[i1 - r - 1], Lc = rp[i1 - r - 2], Ld = rp[i1 - r - 3];
                u16x2 Ra = rp[i1 + r], Rb = rp[i1 + r + 1], Rc = rp[i1 + r + 2], Rd = rp[i1 + r + 3];
                d1 = pkmin(d1, pkmin(pkmin(La + q1, Lb + q2), pkmin(Lc + q3, Ld + q4)));
                d1 = pkmin(d1, pkmin(pkmin(Ra + q1, Rb + q2), pkmin(Rc + q3, Rd + q4)));
            }
            {
                u16x2 La = rp[i2 - r], Lb = rp[i2 - r - 1], Lc = rp[i2 - r - 2], Ld = rp[i2 - r - 3];
                u16x2 Ra = rp[i2 + r], Rb = rp[i2 + r + 1], Rc = rp[i2 + r + 2], Rd = rp[i2 + r + 3];
                d2 = pkmin(d2, pkmin(pkmin(La + q1, Lb + q2), pkmin(Lc + q3, Ld + q4)));
                d2 = pkmin(d2, pkmin(pkmin(Ra + q1, Rb + q2), pkmin(Rc + q3, Rd + q4)));
            }
            u16x2 m = pkmax(pkmax(d0, d1), d2);
            unsigned mm = (m.x > m.y) ? m.x : m.y;
            unsigned thr = (unsigned)((r + 4) * (r + 4));
            if (__all(mm <= thr)) { conv = true; break; }
            r += 4;
            if (r > 37) break;   // processed radii <= 40
        }
        if (!conv) {
            u16x2 m = pkmax(pkmax(d0, d1), d2);
            unsigned mm = (m.x > m.y) ? m.x : m.y;
            if (__any(mm > 1681u)) {
                // exact full-line fallback (float domain), both packed halves
                const float fi0 = (float)i0, fi1 = (float)i1, fi2 = (float)i2;
                float e0l = 3e38f, e0h = 3e38f, e1l = 3e38f, e1h = 3e38f;
                float e2l = 3e38f, e2h = 3e38f;
                for (int j = 0; j < NN; ++j) {
                    u16x2 gv = rp[j];
                    float gl = (float)gv.x, gh = (float)gv.y;
                    float jf = (float)j;
                    float t0 = jf - fi0, t1 = jf - fi1, t2 = jf - fi2;
                    float s0 = t0 * t0, s1 = t1 * t1, s2 = t2 * t2;
                    e0l = fminf(e0l, s0 + gl); e0h = fminf(e0h, s0 + gh);
                    e1l = fminf(e1l, s1 + gl); e1h = fminf(e1h, s1 + gh);
                    e2l = fminf(e2l, s2 + gl); e2h = fminf(e2h, s2 + gh);
                }
                d0.x = (u16)fminf((float)d0.x, e0l); d0.y = (u16)fminf((float)d0.y, e0h);
                d1.x = (u16)fminf((float)d1.x, e1l); d1.y = (u16)fminf((float)d1.y, e1h);
                d2.x = (u16)fminf((float)d2.x, e2l); d2.y = (u16)fminf((float)d2.y, e2h);
            }
        }
        // wave owns this pair row; its reads completed (in-order DS)
        rp[i0] = d0; rp[i1] = d1; rp[i2] = d2;
    }
    __syncthreads();

    // stage out
    if (!FUSE) {
        for (int idx = tid; idx < NN * (PAIRS / 2); idx += 256) {
            int j = idx >> 3, pp = idx & 7;
            uint2 v;
            v.x = ldsw[(2 * pp) * SROW + PADL + j];
            v.y = ldsw[(2 * pp + 1) * SROW + PADL + j];
            *(uint2*)(f + base + (size_t)j * ES + 4 * pp) = v;
        }
    } else {
        for (int idx = tid; idx < NN * (PAIRS / 2); idx += 256) {
            int j = idx >> 3, pp = idx & 7;
            u16x2 wlo = __builtin_bit_cast(u16x2, ldsw[(2 * pp) * SROW + PADL + j]);
            u16x2 whi = __builtin_bit_cast(u16x2, ldsw[(2 * pp + 1) * SROW + PADL + j]);
            size_t ga = base + (size_t)j * ES + 4 * pp;
            ushort4 av = *(const ushort4*)(other + ga);
            float bq[4] = {(float)wlo.x, (float)wlo.y, (float)whi.x, (float)whi.y};
            float aq[4] = {(float)av.x, (float)av.y, (float)av.z, (float)av.w};
            float rq[4];
#pragma unroll
            for (int k = 0; k < 4; ++k) {
                float xx = (sqrtf(aq[k]) - sqrtf(bq[k])) * 0.1f;
                float e = __expf(2.f * xx);
                rq[k] = 1.f - 2.f * __builtin_amdgcn_rcpf(e + 1.f);
            }
            *(float4*)(outp + ga) = *(float4*)(rq);
        }
    }
}

__global__ __launch_bounds__(256, 8) void sdt_ax1A(u16* __restrict__ A) {
    __shared__ __align__(16) u32 ldsw[PAIRS * SROW]; // 17,792 B -> 8 blocks/CU
    pass_tile<NN, false>(A, blockIdx.x, nullptr, nullptr, ldsw);
}

// merged: even g -> axis1 on B (heavy); odd g -> axis0 on A (light, final A)
__global__ __launch_bounds__(256, 8) void sdt_mid(u16* __restrict__ A, u16* __restrict__ B) {
    __shared__ __align__(16) u32 ldsw[PAIRS * SROW];
    int g = blockIdx.x;
    if ((g & 1) == 0) pass_tile<NN, false>(B, g >> 1, nullptr, nullptr, ldsw);
    else              pass_tile<NN2, false>(A, g >> 1, nullptr, nullptr, ldsw);
}

__global__ __launch_bounds__(256, 8) void sdt_ax0Bf(u16* __restrict__ B,
                                                    const u16* __restrict__ A,
                                                    float* __restrict__ outp) {
    __shared__ __align__(16) u32 ldsw[PAIRS * SROW];
    pass_tile<NN2, true>(B, blockIdx.x, A, outp, ldsw);
}

extern "C" void kernel_launch(void* const* d_in, const int* in_sizes, int n_in,
                              void* d_out, int out_size, void* d_ws, size_t ws_size,
                              hipStream_t stream) {
    const float* x = (const float*)d_in[0];
    u16* A = (u16*)d_ws;
    u16* B = (u16*)((char*)d_ws + (size_t)NN3 * 2);
    float* out = (float*)d_out;

    sdt_scan_k<<<NN2 / 4, 256, 0, stream>>>(x, A, B);
    sdt_ax1A<<<1152, 256, 0, stream>>>(A);
    sdt_mid<<<2304, 256, 0, stream>>>(A, B);
    sdt_ax0Bf<<<1152, 256, 0, stream>>>(B, A, out);
}

// Round 8
// 89.409 us; speedup vs baseline: 1.2056x; 1.0904x over previous
//
#include <hip/hip_runtime.h>

// Signed distance transform, N=192^3, exact separable EDT, packed-u16 pipeline.
//   scan (axis 2, contiguous): wave-per-line ballot bitmask EDT -> u16 d^2
//   expansion passes: outward min-plus on PAIRS of k-adjacent lines packed
//       lo/hi u16 in u32 (v_pk_add_u16/v_pk_min_u16), 8 radii per ballot,
//       exit when all d <= (r+8)^2; radii<=40 processed, else exact fallback.
//   dispatch DAG: scan -> P2{ax1(B) | ax1(A)} -> P3{ax0(B) | ax0(A)} -> tanh.
//       heavy (B) tiles first in each mixed dispatch for load balance.
// A = d^2 to nearest zero of x (ws), B = d^2 to nearest nonzero (ws+14MB).

typedef unsigned short u16;
typedef unsigned int   u32;
typedef unsigned long long u64;
typedef u16 u16x2 __attribute__((ext_vector_type(2)));

#define NN    192
#define NN2   (192 * 192)
#define NN3   (192 * 192 * 192)

#define PAIRS 16
#define PADL  40
#define SROW  278            // words: 40 pad + 192 data + 46 pad
#define SENT16 50000
#define SENTPK 0xC350C350u

__device__ __forceinline__ u16x2 pkmin(u16x2 a, u16x2 b) { return __builtin_elementwise_min(a, b); }
__device__ __forceinline__ u16x2 pkmax(u16x2 a, u16x2 b) { return __builtin_elementwise_max(a, b); }

// ---------------------------------------------------------------------------
// Wave-parallel 1D binary EDT along contiguous axis via 192-bit masks.
// ---------------------------------------------------------------------------
__device__ __forceinline__ u64 shr_pair(u64 lo, u64 hi, int s) {
    return (lo >> s) | (s ? (hi << ((64 - s) & 63)) : 0ULL);
}
__device__ __forceinline__ int dist3(u64 a0, u64 a1, u64 a2, int s) {
    u64 w0 = shr_pair(a0, a1, s);
    u64 w1 = shr_pair(a1, a2, s);
    u64 w2 = a2 >> s;
    int t0 = w0 ? __builtin_ctzll(w0) : 255;
    int t1 = w1 ? 64 + __builtin_ctzll(w1) : 255;
    int t2 = w2 ? 128 + __builtin_ctzll(w2) : 255;
    int r = t0 < t1 ? t0 : t1;
    return r < t2 ? r : t2;
}
__device__ __forceinline__ void line_edt(u64 m0, u64 m1, u64 m2, int lane,
                                         u16& o0, u16& o1, u16& o2) {
    u64 r0 = __builtin_bitreverse64(m2);
    u64 r1 = __builtin_bitreverse64(m1);
    u64 r2 = __builtin_bitreverse64(m0);
    const int s = lane, t = 63 - lane;
    int f0 = dist3(m0, m1, m2, s);
    int f1 = dist3(m1, m2, 0ULL, s);
    int f2 = dist3(m2, 0ULL, 0ULL, s);
    int b0 = dist3(r2, 0ULL, 0ULL, t);
    int b1 = dist3(r1, r2, 0ULL, t);
    int b2 = dist3(r0, r1, r2, t);
    int d0 = f0 < b0 ? f0 : b0;
    int d1 = f1 < b1 ? f1 : b1;
    int d2 = f2 < b2 ? f2 : b2;
    o0 = (d0 > 191) ? (u16)65535 : (u16)(d0 * d0);
    o1 = (d1 > 191) ? (u16)65535 : (u16)(d1 * d1);
    o2 = (d2 > 191) ? (u16)65535 : (u16)(d2 * d2);
}

__global__ __launch_bounds__(256) void sdt_scan_k(const float* __restrict__ x,
                                                  u16* __restrict__ A,
                                                  u16* __restrict__ B) {
    const int lane = threadIdx.x & 63;
    const int wid = blockIdx.x * 4 + (threadIdx.x >> 6);
    const size_t base = (size_t)wid * NN;
    float v0 = x[base + lane];
    float v1 = x[base + lane + 64];
    float v2 = x[base + lane + 128];
    u64 m0 = __ballot(v0 != 0.0f);
    u64 m1 = __ballot(v1 != 0.0f);
    u64 m2 = __ballot(v2 != 0.0f);
    u16 a0, a1, a2, b0, b1, b2;
    line_edt(~m0, ~m1, ~m2, lane, a0, a1, a2);
    line_edt(m0, m1, m2, lane, b0, b1, b2);
    A[base + lane] = a0; A[base + lane + 64] = a1; A[base + lane + 128] = a2;
    B[base + lane] = b0; B[base + lane + 64] = b1; B[base + lane + 128] = b2;
}

// ---------------------------------------------------------------------------
// One 32-line tile expansion pass (16 packed pair-rows), in-place u16.
// ES = element stride (NN -> axis 1, NN2 -> axis 0); lines contiguous along k.
// 8 radii per iteration; ballot exit when all d <= (r+8)^2.
// ---------------------------------------------------------------------------
template<long ES>
__device__ __forceinline__ void pass_tile(u16* __restrict__ f, int g, u32* ldsw) {
    const int tid = threadIdx.x;
    const int gp = g / 6, gk = g - 6 * gp;
    const size_t base = (ES == NN ? (size_t)gp * NN2 : (size_t)gp * NN) + (size_t)gk * 32;
    const u16x2 sentv = {(u16)SENT16, (u16)SENT16};

    // sentinel pads: words [0,40) and [232,278) per pair row
    for (int idx = tid; idx < PAIRS * 86; idx += 256) {
        int p = idx / 86, c = idx - p * 86;
        int word = (c < PADL) ? c : (c + NN);
        ldsw[p * SROW + word] = SENTPK;
    }
    // stage in: uint4 = 8 u16 = lines 8q..8q+7 at element j (pairs 4q..4q+3)
    for (int idx = tid; idx < NN * (PAIRS / 4); idx += 256) {
        int j = idx >> 2, q = idx & 3;
        uint4 v = *(const uint4*)(f + base + (size_t)j * ES + 8 * q);
        u32 s0 = __builtin_bit_cast(u32, pkmin(__builtin_bit_cast(u16x2, v.x), sentv));
        u32 s1 = __builtin_bit_cast(u32, pkmin(__builtin_bit_cast(u16x2, v.y), sentv));
        u32 s2 = __builtin_bit_cast(u32, pkmin(__builtin_bit_cast(u16x2, v.z), sentv));
        u32 s3 = __builtin_bit_cast(u32, pkmin(__builtin_bit_cast(u16x2, v.w), sentv));
        int a = PADL + j;
        ldsw[(4 * q + 0) * SROW + a] = s0;
        ldsw[(4 * q + 1) * SROW + a] = s1;
        ldsw[(4 * q + 2) * SROW + a] = s2;
        ldsw[(4 * q + 3) * SROW + a] = s3;
    }
    __syncthreads();

    const int lane = tid & 63;
    const int w = tid >> 6;
    const int i0 = lane, i1 = lane + 64, i2 = lane + 128;

    for (int pp = 0; pp < 4; ++pp) {
        u16x2* rp = (u16x2*)(ldsw + (w * 4 + pp) * SROW + PADL);
        u16x2 d0 = rp[i0], d1 = rp[i1], d2 = rp[i2];

        int r = 1;
        bool conv = false;
        while (true) {
            u16x2 a0 = d0, a1 = d1, a2 = d2;
#pragma unroll
            for (int m = 0; m < 8; ++m) {
                u16 c = (u16)((r + m) * (r + m));
                u16x2 q = {c, c};
                a0 = pkmin(a0, rp[i0 - r - m] + q);
                a0 = pkmin(a0, rp[i0 + r + m] + q);
                a1 = pkmin(a1, rp[i1 - r - m] + q);
                a1 = pkmin(a1, rp[i1 + r + m] + q);
                a2 = pkmin(a2, rp[i2 - r - m] + q);
                a2 = pkmin(a2, rp[i2 + r + m] + q);
            }
            d0 = a0; d1 = a1; d2 = a2;
            u16x2 mv = pkmax(pkmax(d0, d1), d2);
            unsigned mm = (mv.x > mv.y) ? mv.x : mv.y;
            unsigned thr = (unsigned)((r + 8) * (r + 8));
            if (__all(mm <= thr)) { conv = true; break; }
            r += 8;
            if (r > 33) break;   // processed radii <= 40
        }
        if (!conv) {
            u16x2 mv = pkmax(pkmax(d0, d1), d2);
            unsigned mm = (mv.x > mv.y) ? mv.x : mv.y;
            if (__any(mm > 1681u)) {
                // exact full-line fallback (float domain), both packed halves
                const float fi0 = (float)i0, fi1 = (float)i1, fi2 = (float)i2;
                float e0l = 3e38f, e0h = 3e38f, e1l = 3e38f, e1h = 3e38f;
                float e2l = 3e38f, e2h = 3e38f;
                for (int j = 0; j < NN; ++j) {
                    u16x2 gv = rp[j];
                    float gl = (float)gv.x, gh = (float)gv.y;
                    float jf = (float)j;
                    float t0 = jf - fi0, t1 = jf - fi1, t2 = jf - fi2;
                    float s0 = t0 * t0, s1 = t1 * t1, s2 = t2 * t2;
                    e0l = fminf(e0l, s0 + gl); e0h = fminf(e0h, s0 + gh);
                    e1l = fminf(e1l, s1 + gl); e1h = fminf(e1h, s1 + gh);
                    e2l = fminf(e2l, s2 + gl); e2h = fminf(e2h, s2 + gh);
                }
                d0.x = (u16)fminf((float)d0.x, e0l); d0.y = (u16)fminf((float)d0.y, e0h);
                d1.x = (u16)fminf((float)d1.x, e1l); d1.y = (u16)fminf((float)d1.y, e1h);
                d2.x = (u16)fminf((float)d2.x, e2l); d2.y = (u16)fminf((float)d2.y, e2h);
            }
        }
        // wave owns this pair row; its reads completed (in-order DS)
        rp[i0] = d0; rp[i1] = d1; rp[i2] = d2;
    }
    __syncthreads();

    // stage out (uint4)
    for (int idx = tid; idx < NN * (PAIRS / 4); idx += 256) {
        int j = idx >> 2, q = idx & 3;
        int a = PADL + j;
        uint4 v;
        v.x = ldsw[(4 * q + 0) * SROW + a];
        v.y = ldsw[(4 * q + 1) * SROW + a];
        v.z = ldsw[(4 * q + 2) * SROW + a];
        v.w = ldsw[(4 * q + 3) * SROW + a];
        *(uint4*)(f + base + (size_t)j * ES + 8 * q) = v;
    }
}

// P2: g<1152 -> ax1 on B (heavy, first); else ax1 on A (light)
__global__ __launch_bounds__(256, 8) void sdt_p2(u16* __restrict__ A, u16* __restrict__ B) {
    __shared__ __align__(16) u32 ldsw[PAIRS * SROW]; // 17,792 B -> 8 blocks/CU
    int g = blockIdx.x;
    if (g < 1152) pass_tile<NN>(B, g, ldsw);
    else          pass_tile<NN>(A, g - 1152, ldsw);
}

// P3: g<1152 -> ax0 on B (heavier, first); else ax0 on A (light)
__global__ __launch_bounds__(256, 8) void sdt_p3(u16* __restrict__ A, u16* __restrict__ B) {
    __shared__ __align__(16) u32 ldsw[PAIRS * SROW];
    int g = blockIdx.x;
    if (g < 1152) pass_tile<NN2>(B, g, ldsw);
    else          pass_tile<NN2>(A, g - 1152, ldsw);
}

// ---------------------------------------------------------------------------
// Combine: out = tanh((sqrt(A)-sqrt(B))/10), 8 voxels per thread.
// ---------------------------------------------------------------------------
__global__ __launch_bounds__(256) void sdt_combine(const u16* __restrict__ A,
                                                   const u16* __restrict__ B,
                                                   float* __restrict__ out) {
    const size_t i = (size_t)blockIdx.x * 256 + threadIdx.x; // uint4 index
    uint4 va = ((const uint4*)A)[i];
    uint4 vb = ((const uint4*)B)[i];
    u32 wa[4] = {va.x, va.y, va.z, va.w};
    u32 wb[4] = {vb.x, vb.y, vb.z, vb.w};
    float o[8];
#pragma unroll
    for (int m = 0; m < 4; ++m) {
        u16x2 a2 = __builtin_bit_cast(u16x2, wa[m]);
        u16x2 b2 = __builtin_bit_cast(u16x2, wb[m]);
        float x0 = (sqrtf((float)a2.x) - sqrtf((float)b2.x)) * 0.1f;
        float x1 = (sqrtf((float)a2.y) - sqrtf((float)b2.y)) * 0.1f;
        float e0 = __expf(2.f * x0);
        float e1 = __expf(2.f * x1);
        o[2 * m]     = 1.f - 2.f * __builtin_amdgcn_rcpf(e0 + 1.f);
        o[2 * m + 1] = 1.f - 2.f * __builtin_amdgcn_rcpf(e1 + 1.f);
    }
    float4* o4 = (float4*)out;
    o4[2 * i]     = *(float4*)(o);
    o4[2 * i + 1] = *(float4*)(o + 4);
}

extern "C" void kernel_launch(void* const* d_in, const int* in_sizes, int n_in,
                              void* d_out, int out_size, void* d_ws, size_t ws_size,
                              hipStream_t stream) {
    const float* x = (const float*)d_in[0];
    u16* A = (u16*)d_ws;
    u16* B = (u16*)((char*)d_ws + (size_t)NN3 * 2);
    float* out = (float*)d_out;

    sdt_scan_k<<<NN2 / 4, 256, 0, stream>>>(x, A, B);
    sdt_p2<<<2304, 256, 0, stream>>>(A, B);
    sdt_p3<<<2304, 256, 0, stream>>>(A, B);
    sdt_combine<<<NN3 / 8 / 256, 256, 0, stream>>>(A, B, out);
}